// Round 1
// baseline (996.462 us; speedup 1.0000x reference)
//
#include <hip/hip_runtime.h>
#include <hip/hip_bf16.h>

#define T_TOK 4096
#define HIDDEN 3584
#define NQ 28
#define NKV 4
#define HD 128
#define SEQ 1024
#define NQD 3584   // NQ*HD
#define NKVD 512   // NKV*HD
#define QKV_N 4608 // NQD + 2*NKVD

typedef __attribute__((ext_vector_type(8))) short bf16x8;
typedef __attribute__((ext_vector_type(4))) short s16x4;
typedef __attribute__((ext_vector_type(4))) float f32x4;

__device__ __forceinline__ float bf2f(short s) {
  union { unsigned u; float f; } c; c.u = ((unsigned)(unsigned short)s) << 16; return c.f;
}
__device__ __forceinline__ short f2bf(float f) {
  union { float f; unsigned u; } c; c.f = f;
  unsigned u = c.u;
  unsigned r = (u + 0x7FFFu + ((u >> 16) & 1u)) >> 16;
  return (short)r;
}

typedef __attribute__((address_space(1))) const void gvoid;
typedef __attribute__((address_space(3))) void lvoid;
__device__ __forceinline__ void async16(void* l, const void* g) {
  __builtin_amdgcn_global_load_lds((gvoid*)g, (lvoid*)l, 16, 0, 0);
}

// ---------------- prep kernels ----------------

__global__ void cast_hidden(const float* __restrict__ in, short* __restrict__ out, int n4) {
  int i = blockIdx.x * blockDim.x + threadIdx.x;
  if (i >= n4) return;
  float4 v = ((const float4*)in)[i];
  s16x4 o;
  o[0] = f2bf(v.x); o[1] = f2bf(v.y); o[2] = f2bf(v.z); o[3] = f2bf(v.w);
  ((s16x4*)out)[i] = o;
}

__global__ void concat_bias(const float* __restrict__ bq, const float* __restrict__ bk,
                            const float* __restrict__ bv, float* __restrict__ outb) {
  int i = blockIdx.x * blockDim.x + threadIdx.x;
  if (i >= QKV_N) return;
  outb[i] = (i < NQD) ? bq[i] : ((i < NQD + NKVD) ? bk[i - NQD] : bv[i - NQD - NKVD]);
}

// in: fp32 [Kr, Nc] row-major -> out: bf16 [Nc, Kr] row-major (B^T layout)
__global__ __launch_bounds__(256) void transpose_cast(const float* __restrict__ in,
                                                      short* __restrict__ out,
                                                      int Kr, int Nc) {
  __shared__ float tile[32][33];
  int tx = threadIdx.x & 31, ty = threadIdx.x >> 5;
  int c0 = blockIdx.x * 32, r0 = blockIdx.y * 32;
#pragma unroll
  for (int i = 0; i < 4; i++)
    tile[ty + i * 8][tx] = in[(long)(r0 + ty + i * 8) * Nc + c0 + tx];
  __syncthreads();
#pragma unroll
  for (int i = 0; i < 4; i++)
    out[(long)(c0 + ty + i * 8) * Kr + r0 + tx] = f2bf(tile[tx][ty + i * 8]);
}

// ---------------- GEMM: C[M,N] = A[M,K] @ Bt[N,K]^T (+bias) ----------------
// mode 0: store fp32 to Cf.  mode 1: cols <NQD -> bf16 Qo; cols >=NQD -> fp32 KVo[row*1024+..]
__global__ __launch_bounds__(256) void gemm_bt128(
    const short* __restrict__ A, const short* __restrict__ Bt,
    int M, int N, int K,
    const float* __restrict__ bias,
    float* __restrict__ Cf,
    short* __restrict__ Qo, float* __restrict__ KVo,
    int mode)
{
  __shared__ short lds_a[128 * 32];
  __shared__ short lds_b[128 * 32];
  int t = threadIdx.x;
  int w = t >> 6;
  int lane = t & 63;
  int ln = lane & 15, qd = lane >> 4;
  int wm = w >> 1, wn = w & 1;
  int n0 = blockIdx.x * 128, m0 = blockIdx.y * 128;

  const short* ga0 = A + (long)(m0 + (t >> 2)) * K + (t & 3) * 8;
  const short* ga1 = ga0 + (long)64 * K;
  const short* gb0 = Bt + (long)(n0 + (t >> 2)) * K + (t & 3) * 8;
  const short* gb1 = gb0 + (long)64 * K;
  char* lra = (char*)lds_a + w * 1024;
  char* lrb = (char*)lds_b + w * 1024;

  f32x4 acc[4][4];
  f32x4 zf = {0.f, 0.f, 0.f, 0.f};
#pragma unroll
  for (int i = 0; i < 4; i++)
#pragma unroll
    for (int j = 0; j < 4; j++) acc[i][j] = zf;

  int niter = K / 32;
  for (int kt = 0; kt < niter; ++kt) {
    __syncthreads();
    async16(lra, ga0);
    async16(lra + 4096, ga1);
    async16(lrb, gb0);
    async16(lrb + 4096, gb1);
    ga0 += 32; ga1 += 32; gb0 += 32; gb1 += 32;
    __syncthreads();
    bf16x8 af[4], bfr[4];
#pragma unroll
    for (int i = 0; i < 4; i++)
      af[i] = *(const bf16x8*)&lds_a[(wm * 64 + i * 16 + ln) * 32 + qd * 8];
#pragma unroll
    for (int j = 0; j < 4; j++)
      bfr[j] = *(const bf16x8*)&lds_b[(wn * 64 + j * 16 + ln) * 32 + qd * 8];
#pragma unroll
    for (int i = 0; i < 4; i++)
#pragma unroll
      for (int j = 0; j < 4; j++)
        acc[i][j] = __builtin_amdgcn_mfma_f32_16x16x32_bf16(af[i], bfr[j], acc[i][j], 0, 0, 0);
  }

#pragma unroll
  for (int i = 0; i < 4; i++) {
    int grow_base = m0 + wm * 64 + i * 16 + qd * 4;
#pragma unroll
    for (int j = 0; j < 4; j++) {
      int gcol = n0 + wn * 64 + j * 16 + ln;
      float bb = (mode != 0) ? bias[gcol] : 0.f;
#pragma unroll
      for (int r = 0; r < 4; r++) {
        int grow = grow_base + r;
        float v = acc[i][j][r] + bb;
        if (mode == 0) {
          Cf[(long)grow * N + gcol] = v;
        } else {
          if (gcol < NQD) Qo[(long)grow * NQD + gcol] = f2bf(v);
          else KVo[(long)grow * 1024 + (gcol - NQD)] = v;
        }
      }
    }
  }
}

// ---------------- RoPE + kv_fused ----------------
__global__ __launch_bounds__(256) void rope_kernel(
    short* __restrict__ qbf, const int* __restrict__ positions,
    const float* __restrict__ kvraw, float* __restrict__ kv_out,
    short* __restrict__ kbf, short* __restrict__ vbf)
{
  int t = blockIdx.x;
  float pos = (float)positions[t];
  const float c0 = 19.9315685693241740f / 64.0f; // log2(1e6)/64
  int tid = threadIdx.x;

  // Q heads: in-place bf16 rotate
  for (int p = tid; p < NQ * 64; p += 256) {
    int h = p >> 6, i = p & 63;
    float invf = exp2f(-c0 * (float)i);
    float fr = pos * invf;
    float cs = cosf(fr), sn = sinf(fr);
    long base = (long)t * NQD + h * HD + i;
    float x1 = bf2f(qbf[base]), x2 = bf2f(qbf[base + 64]);
    qbf[base] = f2bf(x1 * cs - x2 * sn);
    qbf[base + 64] = f2bf(x2 * cs + x1 * sn);
  }
  // K heads: fp32 precision path for kv_fused
  for (int p = tid; p < NKV * 64; p += 256) {
    int h = p >> 6, i = p & 63;
    float invf = exp2f(-c0 * (float)i);
    float fr = pos * invf;
    float cs = cosf(fr), sn = sinf(fr);
    long base = (long)t * 1024 + h * HD + i;
    float x1 = kvraw[base], x2 = kvraw[base + 64];
    float o1 = x1 * cs - x2 * sn, o2 = x2 * cs + x1 * sn;
    kv_out[base] = o1;
    kv_out[base + 64] = o2;
    int kb = t * NKVD + h * HD + i;
    kbf[kb] = f2bf(o1);
    kbf[kb + 64] = f2bf(o2);
  }
  // V passthrough
  for (int d = tid; d < NKVD; d += 256) {
    long base = (long)t * 1024 + 512 + d;
    float x = kvraw[base];
    kv_out[base] = x;
    vbf[t * NKVD + d] = f2bf(x);
  }
}

// ---------------- Flash attention (causal GQA) ----------------
// grid: b(4) x hq(28) x qtile(16); block 256 = 4 waves; wave w owns q rows [w*16, w*16+16)
__global__ __launch_bounds__(256) void attn_kernel(
    const short* __restrict__ qbf, const short* __restrict__ kbf,
    const short* __restrict__ vbf, short* __restrict__ attn)
{
  __shared__ short k_lds[64 * 128];   // K tile [64 tok][128 dim]; also Q staging
  __shared__ short vt_lds[128 * 72];  // V^T tile [128 dim][64 tok] pad->72
  __shared__ short p_lds[4 * 16 * 72];// per-wave P [16 row][64 col] pad->72

  int t = threadIdx.x;
  int w = t >> 6, lane = t & 63, ln = lane & 15, qd = lane >> 4;
  int qt = blockIdx.x & 15;
  int hq = (blockIdx.x >> 4) % NQ;
  int b = blockIdx.x / (16 * NQ);
  int hkv = hq / 7;
  int tq0 = b * SEQ + qt * 64;
  int tb0 = b * SEQ;

  char* lbase = (char*)k_lds + w * 1024;

  // stage Q tile [64][128] into k_lds
  {
    const short* gq = qbf + (long)(tq0 + (t >> 4)) * NQD + hq * HD + (t & 15) * 8;
#pragma unroll
    for (int i = 0; i < 4; i++)
      async16(lbase + i * 4096, gq + (long)i * 16 * NQD);
  }
  __syncthreads();
  bf16x8 aq[4];
#pragma unroll
  for (int k2 = 0; k2 < 4; k2++)
    aq[k2] = *(const bf16x8*)&k_lds[(w * 16 + ln) * 128 + k2 * 32 + qd * 8];

  f32x4 accO[8];
  f32x4 zf = {0.f, 0.f, 0.f, 0.f};
#pragma unroll
  for (int n = 0; n < 8; n++) accO[n] = zf;
  float m_i[4], l_i[4];
#pragma unroll
  for (int r = 0; r < 4; r++) { m_i[r] = -__builtin_inff(); l_i[r] = 0.f; }

  const float scale = 0.08838834764831845f; // 1/sqrt(128)

  for (int kt = 0; kt <= qt; ++kt) {
    __syncthreads();
    // stage K tile
    {
      const short* gk = kbf + (long)(tb0 + kt * 64 + (t >> 4)) * NKVD + hkv * HD + (t & 15) * 8;
#pragma unroll
      for (int i = 0; i < 4; i++)
        async16(lbase + i * 4096, gk + i * 16 * NKVD);
    }
    // stage V^T
    {
#pragma unroll
      for (int i = 0; i < 4; i++) {
        int r = i * 16 + (t >> 4);
        int d0 = (t & 15) * 8;
        bf16x8 vv = *(const bf16x8*)(vbf + (long)(tb0 + kt * 64 + r) * NKVD + hkv * HD + d0);
#pragma unroll
        for (int jj = 0; jj < 8; jj++)
          vt_lds[(d0 + jj) * 72 + r] = vv[jj];
      }
    }
    __syncthreads();

    // S = (Q K^T) * scale
    f32x4 sc[4];
#pragma unroll
    for (int j = 0; j < 4; j++) {
      f32x4 a = zf;
#pragma unroll
      for (int k2 = 0; k2 < 4; k2++) {
        bf16x8 bk = *(const bf16x8*)&k_lds[(j * 16 + ln) * 128 + k2 * 32 + qd * 8];
        a = __builtin_amdgcn_mfma_f32_16x16x32_bf16(aq[k2], bk, a, 0, 0, 0);
      }
#pragma unroll
      for (int r = 0; r < 4; r++) a[r] *= scale;
      sc[j] = a;
    }

    if (kt == qt) {
#pragma unroll
      for (int j = 0; j < 4; j++) {
        int kcol = j * 16 + ln;
#pragma unroll
        for (int r = 0; r < 4; r++) {
          int qrow = w * 16 + qd * 4 + r;
          if (kcol > qrow) sc[j][r] = -__builtin_inff();
        }
      }
    }

    // online softmax (per-row stats live in lane regs; rows = qd*4+r)
    float alpha[4], rsum[4];
#pragma unroll
    for (int r = 0; r < 4; r++) {
      float mx = fmaxf(fmaxf(sc[0][r], sc[1][r]), fmaxf(sc[2][r], sc[3][r]));
      mx = fmaxf(mx, __shfl_xor(mx, 1));
      mx = fmaxf(mx, __shfl_xor(mx, 2));
      mx = fmaxf(mx, __shfl_xor(mx, 4));
      mx = fmaxf(mx, __shfl_xor(mx, 8));
      float mnew = fmaxf(m_i[r], mx);
      alpha[r] = __expf(m_i[r] - mnew);
      m_i[r] = mnew;
      rsum[r] = 0.f;
    }
#pragma unroll
    for (int j = 0; j < 4; j++) {
#pragma unroll
      for (int r = 0; r < 4; r++) {
        float p = __expf(sc[j][r] - m_i[r]);
        short pb = f2bf(p);
        rsum[r] += bf2f(pb); // normalize what we actually multiply
        p_lds[w * 1152 + (qd * 4 + r) * 72 + j * 16 + ln] = pb;
      }
    }
#pragma unroll
    for (int r = 0; r < 4; r++) {
      rsum[r] += __shfl_xor(rsum[r], 1);
      rsum[r] += __shfl_xor(rsum[r], 2);
      rsum[r] += __shfl_xor(rsum[r], 4);
      rsum[r] += __shfl_xor(rsum[r], 8);
      l_i[r] = l_i[r] * alpha[r] + rsum[r];
    }
#pragma unroll
    for (int n = 0; n < 8; n++)
#pragma unroll
      for (int r = 0; r < 4; r++) accO[n][r] *= alpha[r];

    asm volatile("s_waitcnt lgkmcnt(0)" ::: "memory");

    bf16x8 ap0 = *(const bf16x8*)&p_lds[w * 1152 + ln * 72 + qd * 8];
    bf16x8 ap1 = *(const bf16x8*)&p_lds[w * 1152 + ln * 72 + 32 + qd * 8];
#pragma unroll
    for (int n = 0; n < 8; n++) {
      bf16x8 bv0 = *(const bf16x8*)&vt_lds[(n * 16 + ln) * 72 + qd * 8];
      bf16x8 bv1 = *(const bf16x8*)&vt_lds[(n * 16 + ln) * 72 + 32 + qd * 8];
      accO[n] = __builtin_amdgcn_mfma_f32_16x16x32_bf16(ap0, bv0, accO[n], 0, 0, 0);
      accO[n] = __builtin_amdgcn_mfma_f32_16x16x32_bf16(ap1, bv1, accO[n], 0, 0, 0);
    }
  }

  // epilogue: O /= l, write bf16
#pragma unroll
  for (int r = 0; r < 4; r++) {
    float inv = 1.0f / l_i[r];
    int tok = tq0 + w * 16 + qd * 4 + r;
    long base = (long)tok * NQD + hq * HD;
#pragma unroll
    for (int n = 0; n < 8; n++)
      attn[base + n * 16 + ln] = f2bf(accO[n][r] * inv);
  }
}

// ---------------- launch ----------------
extern "C" void kernel_launch(void* const* d_in, const int* in_sizes, int n_in,
                              void* d_out, int out_size, void* d_ws, size_t ws_size,
                              hipStream_t stream) {
  const float* hidden = (const float*)d_in[0];
  const int* positions = (const int*)d_in[1];
  const float* wq = (const float*)d_in[2];
  const float* bq = (const float*)d_in[3];
  const float* wk = (const float*)d_in[4];
  const float* bk = (const float*)d_in[5];
  const float* wv = (const float*)d_in[6];
  const float* bv = (const float*)d_in[7];
  const float* wo = (const float*)d_in[8];

  float* out = (float*)d_out;                       // [T, 3584]
  float* kv_out = out + (long)T_TOK * NQD;          // [T, 1024]

  char* ws = (char*)d_ws;
  short* hid_bf  = (short*)(ws);                    // T*3584 bf16
  short* wqkvT   = (short*)(ws + 29360128);         // [4608][3584] bf16
  short* woT     = (short*)(ws + 62390272);         // [3584][3584] bf16
  float* biasc   = (float*)(ws + 88080384);         // 4608 f32
  short* q_bf    = (short*)(ws + 88098816);         // T*3584 bf16
  float* kvraw   = (float*)(ws + 117458944);        // T*1024 f32
  short* k_bf    = (short*)(ws + 134236160);        // T*512 bf16
  short* v_bf    = (short*)(ws + 138430464);        // T*512 bf16
  short* attn_bf = (short*)(ws + 142624768);        // T*3584 bf16

  cast_hidden<<<(T_TOK * HIDDEN / 4 + 255) / 256, 256, 0, stream>>>(
      hidden, hid_bf, T_TOK * HIDDEN / 4);
  concat_bias<<<(QKV_N + 255) / 256, 256, 0, stream>>>(bq, bk, bv, biasc);
  transpose_cast<<<dim3(NQD / 32, HIDDEN / 32), 256, 0, stream>>>(wq, wqkvT, HIDDEN, NQD);
  transpose_cast<<<dim3(NKVD / 32, HIDDEN / 32), 256, 0, stream>>>(
      wk, wqkvT + (long)NQD * HIDDEN, HIDDEN, NKVD);
  transpose_cast<<<dim3(NKVD / 32, HIDDEN / 32), 256, 0, stream>>>(
      wv, wqkvT + (long)(NQD + NKVD) * HIDDEN, HIDDEN, NKVD);
  transpose_cast<<<dim3(HIDDEN / 32, NQD / 32), 256, 0, stream>>>(wo, woT, NQD, HIDDEN);

  gemm_bt128<<<dim3(QKV_N / 128, T_TOK / 128), 256, 0, stream>>>(
      hid_bf, wqkvT, T_TOK, QKV_N, HIDDEN, biasc, nullptr, q_bf, kvraw, 1);

  rope_kernel<<<T_TOK, 256, 0, stream>>>(q_bf, positions, kvraw, kv_out, k_bf, v_bf);

  attn_kernel<<<4 * NQ * 16, 256, 0, stream>>>(q_bf, k_bf, v_bf, attn_bf);

  gemm_bt128<<<dim3(HIDDEN / 128, T_TOK / 128), 256, 0, stream>>>(
      attn_bf, woT, T_TOK, HIDDEN, HIDDEN, nullptr, out, nullptr, nullptr, 0);
}

// Round 2
// 747.254 us; speedup vs baseline: 1.3335x; 1.3335x over previous
//
#include <hip/hip_runtime.h>
#include <hip/hip_bf16.h>

#define T_TOK 4096
#define HIDDEN 3584
#define NQ 28
#define NKV 4
#define HD 128
#define SEQ 1024
#define NQD 3584   // NQ*HD
#define NKVD 512   // NKV*HD
#define QKV_N 4608 // NQD + 2*NKVD

typedef __attribute__((ext_vector_type(8))) short bf16x8;
typedef __attribute__((ext_vector_type(4))) short s16x4;
typedef __attribute__((ext_vector_type(4))) float f32x4;

__device__ __forceinline__ float bf2f(short s) {
  union { unsigned u; float f; } c; c.u = ((unsigned)(unsigned short)s) << 16; return c.f;
}
__device__ __forceinline__ short f2bf(float f) {
  union { float f; unsigned u; } c; c.f = f;
  unsigned u = c.u;
  unsigned r = (u + 0x7FFFu + ((u >> 16) & 1u)) >> 16;
  return (short)r;
}

typedef __attribute__((address_space(1))) const void gvoid;
typedef __attribute__((address_space(3))) void lvoid;
__device__ __forceinline__ void async16(void* l, const void* g) {
  __builtin_amdgcn_global_load_lds((gvoid*)g, (lvoid*)l, 16, 0, 0);
}

// ---------------- prep kernels ----------------

__global__ void cast_hidden(const float* __restrict__ in, short* __restrict__ out, int n4) {
  int i = blockIdx.x * blockDim.x + threadIdx.x;
  if (i >= n4) return;
  float4 v = ((const float4*)in)[i];
  s16x4 o;
  o[0] = f2bf(v.x); o[1] = f2bf(v.y); o[2] = f2bf(v.z); o[3] = f2bf(v.w);
  ((s16x4*)out)[i] = o;
}

__global__ void concat_bias(const float* __restrict__ bq, const float* __restrict__ bk,
                            const float* __restrict__ bv, float* __restrict__ outb) {
  int i = blockIdx.x * blockDim.x + threadIdx.x;
  if (i >= QKV_N) return;
  outb[i] = (i < NQD) ? bq[i] : ((i < NQD + NKVD) ? bk[i - NQD] : bv[i - NQD - NKVD]);
}

// in: fp32 [Kr, Nc] row-major -> out: bf16 [Nc, Kr] row-major (B^T layout)
__global__ __launch_bounds__(256) void transpose_cast(const float* __restrict__ in,
                                                      short* __restrict__ out,
                                                      int Kr, int Nc) {
  __shared__ float tile[32][33];
  int tx = threadIdx.x & 31, ty = threadIdx.x >> 5;
  int c0 = blockIdx.x * 32, r0 = blockIdx.y * 32;
#pragma unroll
  for (int i = 0; i < 4; i++)
    tile[ty + i * 8][tx] = in[(long)(r0 + ty + i * 8) * Nc + c0 + tx];
  __syncthreads();
#pragma unroll
  for (int i = 0; i < 4; i++)
    out[(long)(c0 + ty + i * 8) * Kr + r0 + tx] = f2bf(tile[tx][ty + i * 8]);
}

// V transpose: kv_out V-half fp32 [4096 tok][1024 row, cols 512..1023] ->
// vt_g bf16 [(b*4+h)*128 + d][1024 tok-in-seq]
__global__ __launch_bounds__(256) void vtrans(const float* __restrict__ kvo,
                                              short* __restrict__ vtg) {
  __shared__ float tile[32][33];
  int tx = threadIdx.x & 31, ty = threadIdx.x >> 5;
  int c0 = blockIdx.x * 32;   // d     (0..511)
  int r0 = blockIdx.y * 32;   // token (0..4095), 32-tile stays within one seq
  int b = r0 >> 10;
#pragma unroll
  for (int i = 0; i < 4; i++)
    tile[ty + i * 8][tx] = kvo[(long)(r0 + ty + i * 8) * 1024 + 512 + c0 + tx];
  __syncthreads();
#pragma unroll
  for (int i = 0; i < 4; i++) {
    int d = c0 + ty + i * 8;
    vtg[(long)(b * 512 + d) * 1024 + (r0 & 1023) + tx] = f2bf(tile[tx][ty + i * 8]);
  }
}

// ---------------- GEMM: C[M,N] = A[M,K] @ Bt[N,K]^T (+bias) ----------------
// mode 0: store fp32 to Cf.
// mode 1: cols <NQD -> bf16 Qo; NQD..NQD+511 -> fp32 Kraw[row*512+..];
//         >=NQD+512 -> fp32 Vout[row*1024+512+..] (kv_fused V half, final output)
__global__ __launch_bounds__(256) void gemm_bt128(
    const short* __restrict__ A, const short* __restrict__ Bt,
    int M, int N, int K,
    const float* __restrict__ bias,
    float* __restrict__ Cf,
    short* __restrict__ Qo, float* __restrict__ Kraw, float* __restrict__ Vout,
    int mode)
{
  __shared__ short lds_a[128 * 32];
  __shared__ short lds_b[128 * 32];
  int t = threadIdx.x;
  int w = t >> 6;
  int lane = t & 63;
  int ln = lane & 15, qd = lane >> 4;
  int wm = w >> 1, wn = w & 1;
  int n0 = blockIdx.x * 128, m0 = blockIdx.y * 128;

  const short* ga0 = A + (long)(m0 + (t >> 2)) * K + (t & 3) * 8;
  const short* ga1 = ga0 + (long)64 * K;
  const short* gb0 = Bt + (long)(n0 + (t >> 2)) * K + (t & 3) * 8;
  const short* gb1 = gb0 + (long)64 * K;
  char* lra = (char*)lds_a + w * 1024;
  char* lrb = (char*)lds_b + w * 1024;

  f32x4 acc[4][4];
  f32x4 zf = {0.f, 0.f, 0.f, 0.f};
#pragma unroll
  for (int i = 0; i < 4; i++)
#pragma unroll
    for (int j = 0; j < 4; j++) acc[i][j] = zf;

  int niter = K / 32;
  for (int kt = 0; kt < niter; ++kt) {
    __syncthreads();
    async16(lra, ga0);
    async16(lra + 4096, ga1);
    async16(lrb, gb0);
    async16(lrb + 4096, gb1);
    ga0 += 32; ga1 += 32; gb0 += 32; gb1 += 32;
    __syncthreads();
    bf16x8 af[4], bfr[4];
#pragma unroll
    for (int i = 0; i < 4; i++)
      af[i] = *(const bf16x8*)&lds_a[(wm * 64 + i * 16 + ln) * 32 + qd * 8];
#pragma unroll
    for (int j = 0; j < 4; j++)
      bfr[j] = *(const bf16x8*)&lds_b[(wn * 64 + j * 16 + ln) * 32 + qd * 8];
#pragma unroll
    for (int i = 0; i < 4; i++)
#pragma unroll
      for (int j = 0; j < 4; j++)
        acc[i][j] = __builtin_amdgcn_mfma_f32_16x16x32_bf16(af[i], bfr[j], acc[i][j], 0, 0, 0);
  }

#pragma unroll
  for (int i = 0; i < 4; i++) {
    int grow_base = m0 + wm * 64 + i * 16 + qd * 4;
#pragma unroll
    for (int j = 0; j < 4; j++) {
      int gcol = n0 + wn * 64 + j * 16 + ln;
      float bb = (mode != 0) ? bias[gcol] : 0.f;
#pragma unroll
      for (int r = 0; r < 4; r++) {
        int grow = grow_base + r;
        float v = acc[i][j][r] + bb;
        if (mode == 0) {
          Cf[(long)grow * N + gcol] = v;
        } else {
          if (gcol < NQD) Qo[(long)grow * NQD + gcol] = f2bf(v);
          else if (gcol < NQD + NKVD) Kraw[(long)grow * 512 + (gcol - NQD)] = v;
          else Vout[(long)grow * 1024 + 512 + (gcol - NQD - NKVD)] = v;
        }
      }
    }
  }
}

// ---------------- RoPE + kv_fused (K half) ----------------
__global__ __launch_bounds__(256) void rope_kernel(
    short* __restrict__ qbf, const int* __restrict__ positions,
    const float* __restrict__ kraw, float* __restrict__ kv_out,
    short* __restrict__ kbf)
{
  int t = blockIdx.x;
  float pos = (float)positions[t];
  const float c0 = 19.9315685693241740f / 64.0f; // log2(1e6)/64
  int tid = threadIdx.x;

  // Q heads: in-place bf16 rotate
  for (int p = tid; p < NQ * 64; p += 256) {
    int h = p >> 6, i = p & 63;
    float invf = exp2f(-c0 * (float)i);
    float fr = pos * invf;
    float cs = cosf(fr), sn = sinf(fr);
    long base = (long)t * NQD + h * HD + i;
    float x1 = bf2f(qbf[base]), x2 = bf2f(qbf[base + 64]);
    qbf[base] = f2bf(x1 * cs - x2 * sn);
    qbf[base + 64] = f2bf(x2 * cs + x1 * sn);
  }
  // K heads: fp32 precision path for kv_fused
  for (int p = tid; p < NKV * 64; p += 256) {
    int h = p >> 6, i = p & 63;
    float invf = exp2f(-c0 * (float)i);
    float fr = pos * invf;
    float cs = cosf(fr), sn = sinf(fr);
    long kbase = (long)t * 512 + h * HD + i;
    float x1 = kraw[kbase], x2 = kraw[kbase + 64];
    float o1 = x1 * cs - x2 * sn, o2 = x2 * cs + x1 * sn;
    long obase = (long)t * 1024 + h * HD + i;
    kv_out[obase] = o1;
    kv_out[obase + 64] = o2;
    kbf[kbase] = f2bf(o1);
    kbf[kbase + 64] = f2bf(o2);
  }
}

// ---------------- Flash attention (causal GQA), XOR-swizzled LDS ----------------
// grid: b(4) x hq(28) x qtile(16, reversed); block 256 = 4 waves; wave w owns q rows [w*16,+16)
__global__ __launch_bounds__(256, 3) void attn_kernel(
    const short* __restrict__ qbf, const short* __restrict__ kbf,
    const short* __restrict__ vtg, short* __restrict__ attn)
{
  __shared__ short k_lds[64 * 128];    // 16 KB: K tile (also Q staging), swizzled
  __shared__ short v_lds[128 * 64];    // 16 KB: V^T tile [d][tok], swizzled
  __shared__ short p_lds[4 * 16 * 64]; // 8 KB: per-wave P [16 q][64 tok], swizzled

  int t = threadIdx.x;
  int w = t >> 6, lane = t & 63, ln = lane & 15, qd = lane >> 4;
  int qt = 15 - (blockIdx.x & 15);            // big causal tiles dispatch first
  int hq = (blockIdx.x >> 4) % NQ;
  int b = blockIdx.x / (16 * NQ);
  int hkv = hq / 7;
  int tq0 = b * SEQ + qt * 64;
  int tb0 = b * SEQ;

  char* kb = (char*)k_lds;
  char* vb = (char*)v_lds;
  char* pbase = (char*)p_lds + w * 2048;

  // staging geometry: 16B chunks, XOR swizzle chunk ^= (row & mask)
  int krow = t >> 4, kchunk = t & 15;                 // K/Q: 64 rows x 16 chunks
  int kpos0 = krow * 256 + ((kchunk ^ krow) & 15) * 16;  // +i*4096 (row += 16)
  int vrow = t >> 3, vchunk = t & 7;                  // V^T: 128 rows x 8 chunks
  int vpos0 = vrow * 128 + ((vchunk ^ vrow) & 7) * 16;   // +i*4096 (row += 32)

  const short* kptr = kbf + (long)(tb0 + krow) * 512 + hkv * 128 + kchunk * 8;
  const short* vptr = vtg + (long)((b * 4 + hkv) * 128 + vrow) * 1024 + vchunk * 8;
  const short* qptr = qbf + (long)(tq0 + krow) * NQD + hq * 128 + kchunk * 8;

  bf16x8 kreg[4], vreg[4], qreg[4];
#pragma unroll
  for (int i = 0; i < 4; i++) {
    qreg[i] = *(const bf16x8*)(qptr + (long)i * 16 * NQD);
    kreg[i] = *(const bf16x8*)(kptr + i * 16 * 512);
    vreg[i] = *(const bf16x8*)(vptr + i * 32 * 1024);
  }
#pragma unroll
  for (int i = 0; i < 4; i++)
    *(bf16x8*)(kb + kpos0 + i * 4096) = qreg[i];
  __syncthreads();

  bf16x8 aq[4];
#pragma unroll
  for (int k2 = 0; k2 < 4; k2++)
    aq[k2] = *(const bf16x8*)(kb + (w * 16 + ln) * 256 + (((k2 * 4 + qd) ^ ln) & 15) * 16);

  f32x4 accO[8];
  f32x4 zf = {0.f, 0.f, 0.f, 0.f};
#pragma unroll
  for (int n = 0; n < 8; n++) accO[n] = zf;
  float m_i[4], l_i[4];
#pragma unroll
  for (int r = 0; r < 4; r++) { m_i[r] = -__builtin_inff(); l_i[r] = 0.f; }

  const float scale = 0.08838834764831845f; // 1/sqrt(128)

  for (int kt = 0; kt <= qt; ++kt) {
    __syncthreads();   // prior reads of k_lds/v_lds complete
#pragma unroll
    for (int i = 0; i < 4; i++) {
      *(bf16x8*)(kb + kpos0 + i * 4096) = kreg[i];
      *(bf16x8*)(vb + vpos0 + i * 4096) = vreg[i];
    }
    __syncthreads();   // tiles visible
    if (kt < qt) {     // prefetch next tile into regs, hidden behind compute
      kptr += 64 * 512;
      vptr += 64;
#pragma unroll
      for (int i = 0; i < 4; i++) {
        kreg[i] = *(const bf16x8*)(kptr + i * 16 * 512);
        vreg[i] = *(const bf16x8*)(vptr + i * 32 * 1024);
      }
    }

    // S = (Q K^T) * scale
    f32x4 sc[4];
#pragma unroll
    for (int j = 0; j < 4; j++) {
      f32x4 a = zf;
#pragma unroll
      for (int k2 = 0; k2 < 4; k2++) {
        bf16x8 bk = *(const bf16x8*)(kb + (j * 16 + ln) * 256 + (((k2 * 4 + qd) ^ ln) & 15) * 16);
        a = __builtin_amdgcn_mfma_f32_16x16x32_bf16(aq[k2], bk, a, 0, 0, 0);
      }
#pragma unroll
      for (int r = 0; r < 4; r++) a[r] *= scale;
      sc[j] = a;
    }

    if (kt == qt) {
#pragma unroll
      for (int j = 0; j < 4; j++) {
        int kcol = j * 16 + ln;
#pragma unroll
        for (int r = 0; r < 4; r++) {
          int qrow = w * 16 + qd * 4 + r;
          if (kcol > qrow) sc[j][r] = -__builtin_inff();
        }
      }
    }

    // online softmax (rows = qd*4+r)
    float alpha[4], rsum[4];
#pragma unroll
    for (int r = 0; r < 4; r++) {
      float mx = fmaxf(fmaxf(sc[0][r], sc[1][r]), fmaxf(sc[2][r], sc[3][r]));
      mx = fmaxf(mx, __shfl_xor(mx, 1));
      mx = fmaxf(mx, __shfl_xor(mx, 2));
      mx = fmaxf(mx, __shfl_xor(mx, 4));
      mx = fmaxf(mx, __shfl_xor(mx, 8));
      float mnew = fmaxf(m_i[r], mx);
      alpha[r] = __expf(m_i[r] - mnew);
      m_i[r] = mnew;
      rsum[r] = 0.f;
    }
#pragma unroll
    for (int j = 0; j < 4; j++) {
#pragma unroll
      for (int r = 0; r < 4; r++) {
        float p = __expf(sc[j][r] - m_i[r]);
        short pb = f2bf(p);
        rsum[r] += bf2f(pb); // normalize exactly what we multiply
        int row_p = qd * 4 + r;
        // P[row_p][j*16+ln] -> chunk (j*2 + (ln>>3)) ^ (row_p&7), short offset ln&7
        *(short*)(pbase + row_p * 128 + (((j * 2 + (ln >> 3)) ^ row_p) & 7) * 16 + (ln & 7) * 2) = pb;
      }
    }
#pragma unroll
    for (int r = 0; r < 4; r++) {
      rsum[r] += __shfl_xor(rsum[r], 1);
      rsum[r] += __shfl_xor(rsum[r], 2);
      rsum[r] += __shfl_xor(rsum[r], 4);
      rsum[r] += __shfl_xor(rsum[r], 8);
      l_i[r] = l_i[r] * alpha[r] + rsum[r];
    }
#pragma unroll
    for (int n = 0; n < 8; n++)
#pragma unroll
      for (int r = 0; r < 4; r++) accO[n][r] *= alpha[r];

    asm volatile("s_waitcnt lgkmcnt(0)" ::: "memory");

    bf16x8 ap0 = *(const bf16x8*)(pbase + ln * 128 + ((qd ^ ln) & 7) * 16);
    bf16x8 ap1 = *(const bf16x8*)(pbase + ln * 128 + (((4 + qd) ^ ln) & 7) * 16);
#pragma unroll
    for (int n = 0; n < 8; n++) {
      bf16x8 bv0 = *(const bf16x8*)(vb + (n * 16 + ln) * 128 + ((qd ^ ln) & 7) * 16);
      bf16x8 bv1 = *(const bf16x8*)(vb + (n * 16 + ln) * 128 + (((4 + qd) ^ ln) & 7) * 16);
      accO[n] = __builtin_amdgcn_mfma_f32_16x16x32_bf16(ap0, bv0, accO[n], 0, 0, 0);
      accO[n] = __builtin_amdgcn_mfma_f32_16x16x32_bf16(ap1, bv1, accO[n], 0, 0, 0);
    }
  }

  // epilogue: O /= l, write bf16
#pragma unroll
  for (int r = 0; r < 4; r++) {
    float inv = 1.0f / l_i[r];
    int tok = tq0 + w * 16 + qd * 4 + r;
    long base = (long)tok * NQD + hq * HD;
#pragma unroll
    for (int n = 0; n < 8; n++)
      attn[base + n * 16 + ln] = f2bf(accO[n][r] * inv);
  }
}

// ---------------- launch ----------------
extern "C" void kernel_launch(void* const* d_in, const int* in_sizes, int n_in,
                              void* d_out, int out_size, void* d_ws, size_t ws_size,
                              hipStream_t stream) {
  const float* hidden = (const float*)d_in[0];
  const int* positions = (const int*)d_in[1];
  const float* wq = (const float*)d_in[2];
  const float* bq = (const float*)d_in[3];
  const float* wk = (const float*)d_in[4];
  const float* bk = (const float*)d_in[5];
  const float* wv = (const float*)d_in[6];
  const float* bv = (const float*)d_in[7];
  const float* wo = (const float*)d_in[8];

  float* out = (float*)d_out;                       // [T, 3584]
  float* kv_out = out + (long)T_TOK * NQD;          // [T, 1024] (kv_fused)

  char* ws = (char*)d_ws;
  short* hid_bf  = (short*)(ws);                    // T*3584 bf16
  short* wqkvT   = (short*)(ws + 29360128);         // [4608][3584] bf16
  short* woT     = (short*)(ws + 62390272);         // [3584][3584] bf16
  float* biasc   = (float*)(ws + 88080384);         // 4608 f32
  short* q_bf    = (short*)(ws + 88098816);         // T*3584 bf16
  float* kraw    = (float*)(ws + 117458944);        // T*512 f32
  short* k_bf    = (short*)(ws + 125847552);        // T*512 bf16
  short* vt_g    = (short*)(ws + 130041856);        // [16*128][1024] bf16 (V^T per b,h)
  short* attn_bf = (short*)(ws + 134236160);        // T*3584 bf16

  cast_hidden<<<(T_TOK * HIDDEN / 4 + 255) / 256, 256, 0, stream>>>(
      hidden, hid_bf, T_TOK * HIDDEN / 4);
  concat_bias<<<(QKV_N + 255) / 256, 256, 0, stream>>>(bq, bk, bv, biasc);
  transpose_cast<<<dim3(NQD / 32, HIDDEN / 32), 256, 0, stream>>>(wq, wqkvT, HIDDEN, NQD);
  transpose_cast<<<dim3(NKVD / 32, HIDDEN / 32), 256, 0, stream>>>(
      wk, wqkvT + (long)NQD * HIDDEN, HIDDEN, NKVD);
  transpose_cast<<<dim3(NKVD / 32, HIDDEN / 32), 256, 0, stream>>>(
      wv, wqkvT + (long)(NQD + NKVD) * HIDDEN, HIDDEN, NKVD);
  transpose_cast<<<dim3(HIDDEN / 32, NQD / 32), 256, 0, stream>>>(wo, woT, NQD, HIDDEN);

  gemm_bt128<<<dim3(QKV_N / 128, T_TOK / 128), 256, 0, stream>>>(
      hid_bf, wqkvT, T_TOK, QKV_N, HIDDEN, biasc, nullptr, q_bf, kraw, kv_out, 1);

  vtrans<<<dim3(NKVD / 32, T_TOK / 32), 256, 0, stream>>>(kv_out, vt_g);

  rope_kernel<<<T_TOK, 256, 0, stream>>>(q_bf, positions, kraw, kv_out, k_bf);

  attn_kernel<<<4 * NQ * 16, 256, 0, stream>>>(q_bf, k_bf, vt_g, attn_bf);

  gemm_bt128<<<dim3(HIDDEN / 128, T_TOK / 128), 256, 0, stream>>>(
      attn_bf, woT, T_TOK, HIDDEN, HIDDEN, nullptr, out, nullptr, nullptr, nullptr, 0);
}

// Round 4
// 704.470 us; speedup vs baseline: 1.4145x; 1.0607x over previous
//
#include <hip/hip_runtime.h>
#include <hip/hip_bf16.h>

#define T_TOK 4096
#define HIDDEN 3584
#define NQ 28
#define NKV 4
#define HD 128
#define SEQ 1024
#define NQD 3584   // NQ*HD
#define NKVD 512   // NKV*HD
#define QKV_N 4608 // NQD + 2*NKVD

typedef __attribute__((ext_vector_type(8))) short bf16x8;
typedef __attribute__((ext_vector_type(4))) short s16x4;
typedef __attribute__((ext_vector_type(4))) float f32x4;

__device__ __forceinline__ float bf2f(short s) {
  union { unsigned u; float f; } c; c.u = ((unsigned)(unsigned short)s) << 16; return c.f;
}
__device__ __forceinline__ short f2bf(float f) {
  union { float f; unsigned u; } c; c.f = f;
  unsigned u = c.u;
  unsigned r = (u + 0x7FFFu + ((u >> 16) & 1u)) >> 16;
  return (short)r;
}

typedef __attribute__((address_space(1))) const void gvoid;
typedef __attribute__((address_space(3))) void lvoid;
__device__ __forceinline__ void async16(void* l, const void* g) {
  __builtin_amdgcn_global_load_lds((gvoid*)g, (lvoid*)l, 16, 0, 0);
}

// ---------------- prep kernels ----------------

__global__ void cast_hidden(const float* __restrict__ in, short* __restrict__ out, int n4) {
  int i = blockIdx.x * blockDim.x + threadIdx.x;
  if (i >= n4) return;
  float4 v = ((const float4*)in)[i];
  s16x4 o;
  o[0] = f2bf(v.x); o[1] = f2bf(v.y); o[2] = f2bf(v.z); o[3] = f2bf(v.w);
  ((s16x4*)out)[i] = o;
}

__global__ void concat_bias(const float* __restrict__ bq, const float* __restrict__ bk,
                            const float* __restrict__ bv, float* __restrict__ outb) {
  int i = blockIdx.x * blockDim.x + threadIdx.x;
  if (i >= QKV_N) return;
  outb[i] = (i < NQD) ? bq[i] : ((i < NQD + NKVD) ? bk[i - NQD] : bv[i - NQD - NKVD]);
}

// in: fp32 [R, C] row-major -> out: bf16 [C, R] row-major. R,C multiples of 64.
__global__ __launch_bounds__(256) void transpose_cast64(const float* __restrict__ in,
                                                        short* __restrict__ out,
                                                        int R, int C) {
  __shared__ short tile[64][80];  // [c][r], stride 160 B
  int t = threadIdx.x;
  int c0 = blockIdx.x * 64, r0 = blockIdx.y * 64;
  int ty = t >> 4;            // 0..15
  int tx = (t & 15) * 4;      // 0..60
#pragma unroll
  for (int i = 0; i < 4; i++) {
    int r = ty + i * 16;
    float4 v = *(const float4*)&in[(long)(r0 + r) * C + c0 + tx];
    tile[tx + 0][r] = f2bf(v.x);
    tile[tx + 1][r] = f2bf(v.y);
    tile[tx + 2][r] = f2bf(v.z);
    tile[tx + 3][r] = f2bf(v.w);
  }
  __syncthreads();
  int c = t >> 2;             // 0..63
  int rc = (t & 3) * 16;      // 16-short chunk -> two bf16x8 stores
  *(bf16x8*)&out[(long)(c0 + c) * R + r0 + rc]     = *(const bf16x8*)&tile[c][rc];
  *(bf16x8*)&out[(long)(c0 + c) * R + r0 + rc + 8] = *(const bf16x8*)&tile[c][rc + 8];
}

// V transpose: kv_out V-half fp32 [4096 tok][1024, cols 512..1023] ->
// vt_g bf16 [(b*4+h)*128 + d][1024 tok-in-seq]
__global__ __launch_bounds__(256) void vtrans64(const float* __restrict__ kvo,
                                                short* __restrict__ vtg) {
  __shared__ short tile[64][80];
  int t = threadIdx.x;
  int d0 = blockIdx.x * 64;   // 0..511
  int t0 = blockIdx.y * 64;   // token 0..4095 (stays within one seq)
  int b = t0 >> 10;
  int ty = t >> 4, tx = (t & 15) * 4;
#pragma unroll
  for (int i = 0; i < 4; i++) {
    int r = ty + i * 16;
    float4 v = *(const float4*)&kvo[(long)(t0 + r) * 1024 + 512 + d0 + tx];
    tile[tx + 0][r] = f2bf(v.x);
    tile[tx + 1][r] = f2bf(v.y);
    tile[tx + 2][r] = f2bf(v.z);
    tile[tx + 3][r] = f2bf(v.w);
  }
  __syncthreads();
  int d = t >> 2;
  int rc = (t & 3) * 16;
  long ob = (long)(b * 512 + d0 + d) * 1024 + (t0 & 1023) + rc;
  *(bf16x8*)&vtg[ob]     = *(const bf16x8*)&tile[d][rc];
  *(bf16x8*)&vtg[ob + 8] = *(const bf16x8*)&tile[d][rc + 8];
}

// ---------------- GEMM: C[M,N] = A[M,K] @ Bt[N,K]^T (+bias) ----------------
// Single-barrier double-buffered K-loop + grouped rasterization.
// mode 0: fp32 to Cf.  mode 1: Q cols -> bf16 Qo; K cols -> fp32 Kraw; V cols -> fp32 Vout.
__global__ __launch_bounds__(256, 3) void gemm_bt128(
    const short* __restrict__ A, const short* __restrict__ Bt,
    int M, int N, int K,
    const float* __restrict__ bias,
    float* __restrict__ Cf,
    short* __restrict__ Qo, float* __restrict__ Kraw, float* __restrict__ Vout,
    int mode)
{
  __shared__ short lds_a[2][128 * 32];
  __shared__ short lds_b[2][128 * 32];
  int t = threadIdx.x;
  int w = t >> 6;
  int lane = t & 63;
  int ln = lane & 15, qd = lane >> 4;
  int wm = w >> 1, wn = w & 1;

  // grouped rasterization: 8 M-tiles per group, n varies slowly within group
  int GN = N >> 7, GM = M >> 7;
  int pid = blockIdx.x;
  int width = 8 * GN;
  int group = pid / width;
  int rem = pid - group * width;
  int gsize = min(8, GM - group * 8);
  int mti = group * 8 + rem % gsize;
  int nti = rem / gsize;
  int m0 = mti << 7, n0 = nti << 7;

  const short* ga0 = A + (long)(m0 + (t >> 2)) * K + (t & 3) * 8;
  const short* ga1 = ga0 + (long)64 * K;
  const short* gb0 = Bt + (long)(n0 + (t >> 2)) * K + (t & 3) * 8;
  const short* gb1 = gb0 + (long)64 * K;

  f32x4 acc[4][4];
  f32x4 zf = {0.f, 0.f, 0.f, 0.f};
#pragma unroll
  for (int i = 0; i < 4; i++)
#pragma unroll
    for (int j = 0; j < 4; j++) acc[i][j] = zf;

  int niter = K / 32;

  // prologue: stage tile 0 into buffer 0
  {
    char* la = (char*)&lds_a[0][0] + w * 1024;
    char* lb = (char*)&lds_b[0][0] + w * 1024;
    async16(la, ga0);
    async16(la + 4096, ga1);
    async16(lb, gb0);
    async16(lb + 4096, gb1);
    ga0 += 32; ga1 += 32; gb0 += 32; gb1 += 32;
  }

  for (int kt = 0; kt < niter; ++kt) {
    __syncthreads();  // drain: buf[kt&1] ready, buf[kt&1^1] free
    int cur = kt & 1;
    int nxt = cur ^ 1;

    bf16x8 af[4], bfr[4];
#pragma unroll
    for (int i = 0; i < 4; i++)
      af[i] = *(const bf16x8*)&lds_a[cur][(wm * 64 + i * 16 + ln) * 32 + qd * 8];
#pragma unroll
    for (int j = 0; j < 4; j++)
      bfr[j] = *(const bf16x8*)&lds_b[cur][(wn * 64 + j * 16 + ln) * 32 + qd * 8];

    if (kt + 1 < niter) {  // prefetch next tile; completes during MFMA phase
      char* la = (char*)&lds_a[nxt][0] + w * 1024;
      char* lb = (char*)&lds_b[nxt][0] + w * 1024;
      async16(la, ga0);
      async16(la + 4096, ga1);
      async16(lb, gb0);
      async16(lb + 4096, gb1);
      ga0 += 32; ga1 += 32; gb0 += 32; gb1 += 32;
    }

#pragma unroll
    for (int i = 0; i < 4; i++)
#pragma unroll
      for (int j = 0; j < 4; j++)
        acc[i][j] = __builtin_amdgcn_mfma_f32_16x16x32_bf16(af[i], bfr[j], acc[i][j], 0, 0, 0);
  }

  // epilogue — tile-uniform output routing (NQD, NQD+NKVD are multiples of 128)
  if (mode == 0) {
#pragma unroll
    for (int i = 0; i < 4; i++) {
      int grow_base = m0 + wm * 64 + i * 16 + qd * 4;
#pragma unroll
      for (int j = 0; j < 4; j++) {
        int gcol = n0 + wn * 64 + j * 16 + ln;
#pragma unroll
        for (int r = 0; r < 4; r++)
          Cf[(long)(grow_base + r) * N + gcol] = acc[i][j][r];
      }
    }
  } else if (n0 < NQD) {  // Q columns -> bf16
#pragma unroll
    for (int i = 0; i < 4; i++) {
      int grow_base = m0 + wm * 64 + i * 16 + qd * 4;
#pragma unroll
      for (int j = 0; j < 4; j++) {
        int gcol = n0 + wn * 64 + j * 16 + ln;
        float bb = bias[gcol];
#pragma unroll
        for (int r = 0; r < 4; r++)
          Qo[(long)(grow_base + r) * NQD + gcol] = f2bf(acc[i][j][r] + bb);
      }
    }
  } else if (n0 < NQD + NKVD) {  // K columns -> fp32 raw
#pragma unroll
    for (int i = 0; i < 4; i++) {
      int grow_base = m0 + wm * 64 + i * 16 + qd * 4;
#pragma unroll
      for (int j = 0; j < 4; j++) {
        int gcol = n0 + wn * 64 + j * 16 + ln;
        float bb = bias[gcol];
#pragma unroll
        for (int r = 0; r < 4; r++)
          Kraw[(long)(grow_base + r) * 512 + (gcol - NQD)] = acc[i][j][r] + bb;
      }
    }
  } else {  // V columns -> fp32 into kv_fused V half (final output)
#pragma unroll
    for (int i = 0; i < 4; i++) {
      int grow_base = m0 + wm * 64 + i * 16 + qd * 4;
#pragma unroll
      for (int j = 0; j < 4; j++) {
        int gcol = n0 + wn * 64 + j * 16 + ln;
        float bb = bias[gcol];
#pragma unroll
        for (int r = 0; r < 4; r++)
          Vout[(long)(grow_base + r) * 1024 + 512 + (gcol - NQD - NKVD)] = acc[i][j][r] + bb;
      }
    }
  }
}

// ---------------- RoPE + kv_fused (K half) ----------------
__global__ __launch_bounds__(256) void rope_kernel(
    short* __restrict__ qbf, const int* __restrict__ positions,
    const float* __restrict__ kraw, float* __restrict__ kv_out,
    short* __restrict__ kbf)
{
  int t = blockIdx.x;
  float pos = (float)positions[t];
  const float c0 = 19.9315685693241740f / 64.0f; // log2(1e6)/64
  int tid = threadIdx.x;

  for (int p = tid; p < NQ * 64; p += 256) {
    int h = p >> 6, i = p & 63;
    float invf = exp2f(-c0 * (float)i);
    float fr = pos * invf;
    float cs = cosf(fr), sn = sinf(fr);
    long base = (long)t * NQD + h * HD + i;
    float x1 = bf2f(qbf[base]), x2 = bf2f(qbf[base + 64]);
    qbf[base] = f2bf(x1 * cs - x2 * sn);
    qbf[base + 64] = f2bf(x2 * cs + x1 * sn);
  }
  for (int p = tid; p < NKV * 64; p += 256) {
    int h = p >> 6, i = p & 63;
    float invf = exp2f(-c0 * (float)i);
    float fr = pos * invf;
    float cs = cosf(fr), sn = sinf(fr);
    long kbase = (long)t * 512 + h * HD + i;
    float x1 = kraw[kbase], x2 = kraw[kbase + 64];
    float o1 = x1 * cs - x2 * sn, o2 = x2 * cs + x1 * sn;
    long obase = (long)t * 1024 + h * HD + i;
    kv_out[obase] = o1;
    kv_out[obase + 64] = o2;
    kbf[kbase] = f2bf(o1);
    kbf[kbase + 64] = f2bf(o2);
  }
}

// ---------------- Flash attention (causal GQA), XOR-swizzled LDS ----------------
__global__ __launch_bounds__(256, 3) void attn_kernel(
    const short* __restrict__ qbf, const short* __restrict__ kbf,
    const short* __restrict__ vtg, short* __restrict__ attn)
{
  __shared__ short k_lds[64 * 128];
  __shared__ short v_lds[128 * 64];
  __shared__ short p_lds[4 * 16 * 64];

  int t = threadIdx.x;
  int w = t >> 6, lane = t & 63, ln = lane & 15, qd = lane >> 4;
  int qt = 15 - (blockIdx.x & 15);
  int hq = (blockIdx.x >> 4) % NQ;
  int b = blockIdx.x / (16 * NQ);
  int hkv = hq / 7;
  int tq0 = b * SEQ + qt * 64;
  int tb0 = b * SEQ;

  char* kb = (char*)k_lds;
  char* vb = (char*)v_lds;
  char* pbase = (char*)p_lds + w * 2048;

  int krow = t >> 4, kchunk = t & 15;
  int kpos0 = krow * 256 + ((kchunk ^ krow) & 15) * 16;
  int vrow = t >> 3, vchunk = t & 7;
  int vpos0 = vrow * 128 + ((vchunk ^ vrow) & 7) * 16;

  const short* kptr = kbf + (long)(tb0 + krow) * 512 + hkv * 128 + kchunk * 8;
  const short* vptr = vtg + (long)((b * 4 + hkv) * 128 + vrow) * 1024 + vchunk * 8;
  const short* qptr = qbf + (long)(tq0 + krow) * NQD + hq * 128 + kchunk * 8;

  bf16x8 kreg[4], vreg[4], qreg[4];
#pragma unroll
  for (int i = 0; i < 4; i++) {
    qreg[i] = *(const bf16x8*)(qptr + (long)i * 16 * NQD);
    kreg[i] = *(const bf16x8*)(kptr + i * 16 * 512);
    vreg[i] = *(const bf16x8*)(vptr + i * 32 * 1024);
  }
#pragma unroll
  for (int i = 0; i < 4; i++)
    *(bf16x8*)(kb + kpos0 + i * 4096) = qreg[i];
  __syncthreads();

  bf16x8 aq[4];
#pragma unroll
  for (int k2 = 0; k2 < 4; k2++)
    aq[k2] = *(const bf16x8*)(kb + (w * 16 + ln) * 256 + (((k2 * 4 + qd) ^ ln) & 15) * 16);

  f32x4 accO[8];
  f32x4 zf = {0.f, 0.f, 0.f, 0.f};
#pragma unroll
  for (int n = 0; n < 8; n++) accO[n] = zf;
  float m_i[4], l_i[4];
#pragma unroll
  for (int r = 0; r < 4; r++) { m_i[r] = -__builtin_inff(); l_i[r] = 0.f; }

  const float scale = 0.08838834764831845f;

  for (int kt = 0; kt <= qt; ++kt) {
    __syncthreads();
#pragma unroll
    for (int i = 0; i < 4; i++) {
      *(bf16x8*)(kb + kpos0 + i * 4096) = kreg[i];
      *(bf16x8*)(vb + vpos0 + i * 4096) = vreg[i];
    }
    __syncthreads();
    if (kt < qt) {
      kptr += 64 * 512;
      vptr += 64;
#pragma unroll
      for (int i = 0; i < 4; i++) {
        kreg[i] = *(const bf16x8*)(kptr + i * 16 * 512);
        vreg[i] = *(const bf16x8*)(vptr + i * 32 * 1024);
      }
    }

    f32x4 sc[4];
#pragma unroll
    for (int j = 0; j < 4; j++) {
      f32x4 a = zf;
#pragma unroll
      for (int k2 = 0; k2 < 4; k2++) {
        bf16x8 bk = *(const bf16x8*)(kb + (j * 16 + ln) * 256 + (((k2 * 4 + qd) ^ ln) & 15) * 16);
        a = __builtin_amdgcn_mfma_f32_16x16x32_bf16(aq[k2], bk, a, 0, 0, 0);
      }
#pragma unroll
      for (int r = 0; r < 4; r++) a[r] *= scale;
      sc[j] = a;
    }

    if (kt == qt) {
#pragma unroll
      for (int j = 0; j < 4; j++) {
        int kcol = j * 16 + ln;
#pragma unroll
        for (int r = 0; r < 4; r++) {
          int qrow = w * 16 + qd * 4 + r;
          if (kcol > qrow) sc[j][r] = -__builtin_inff();
        }
      }
    }

    float alpha[4], rsum[4];
#pragma unroll
    for (int r = 0; r < 4; r++) {
      float mx = fmaxf(fmaxf(sc[0][r], sc[1][r]), fmaxf(sc[2][r], sc[3][r]));
      mx = fmaxf(mx, __shfl_xor(mx, 1));
      mx = fmaxf(mx, __shfl_xor(mx, 2));
      mx = fmaxf(mx, __shfl_xor(mx, 4));
      mx = fmaxf(mx, __shfl_xor(mx, 8));
      float mnew = fmaxf(m_i[r], mx);
      alpha[r] = __expf(m_i[r] - mnew);
      m_i[r] = mnew;
      rsum[r] = 0.f;
    }
#pragma unroll
    for (int j = 0; j < 4; j++) {
#pragma unroll
      for (int r = 0; r < 4; r++) {
        float p = __expf(sc[j][r] - m_i[r]);
        short pb = f2bf(p);
        rsum[r] += bf2f(pb);
        int row_p = qd * 4 + r;
        *(short*)(pbase + row_p * 128 + (((j * 2 + (ln >> 3)) ^ row_p) & 7) * 16 + (ln & 7) * 2) = pb;
      }
    }
#pragma unroll
    for (int r = 0; r < 4; r++) {
      rsum[r] += __shfl_xor(rsum[r], 1);
      rsum[r] += __shfl_xor(rsum[r], 2);
      rsum[r] += __shfl_xor(rsum[r], 4);
      rsum[r] += __shfl_xor(rsum[r], 8);
      l_i[r] = l_i[r] * alpha[r] + rsum[r];
    }
#pragma unroll
    for (int n = 0; n < 8; n++)
#pragma unroll
      for (int r = 0; r < 4; r++) accO[n][r] *= alpha[r];

    asm volatile("s_waitcnt lgkmcnt(0)" ::: "memory");

    bf16x8 ap0 = *(const bf16x8*)(pbase + ln * 128 + ((qd ^ ln) & 7) * 16);
    bf16x8 ap1 = *(const bf16x8*)(pbase + ln * 128 + (((4 + qd) ^ ln) & 7) * 16);
#pragma unroll
    for (int n = 0; n < 8; n++) {
      bf16x8 bv0 = *(const bf16x8*)(vb + (n * 16 + ln) * 128 + ((qd ^ ln) & 7) * 16);
      bf16x8 bv1 = *(const bf16x8*)(vb + (n * 16 + ln) * 128 + (((4 + qd) ^ ln) & 7) * 16);
      accO[n] = __builtin_amdgcn_mfma_f32_16x16x32_bf16(ap0, bv0, accO[n], 0, 0, 0);
      accO[n] = __builtin_amdgcn_mfma_f32_16x16x32_bf16(ap1, bv1, accO[n], 0, 0, 0);
    }
  }

#pragma unroll
  for (int r = 0; r < 4; r++) {
    float inv = 1.0f / l_i[r];
    int tok = tq0 + w * 16 + qd * 4 + r;
    long base = (long)tok * NQD + hq * HD;
#pragma unroll
    for (int n = 0; n < 8; n++)
      attn[base + n * 16 + ln] = f2bf(accO[n][r] * inv);
  }
}

// ---------------- launch ----------------
extern "C" void kernel_launch(void* const* d_in, const int* in_sizes, int n_in,
                              void* d_out, int out_size, void* d_ws, size_t ws_size,
                              hipStream_t stream) {
  const float* hidden = (const float*)d_in[0];
  const int* positions = (const int*)d_in[1];
  const float* wq = (const float*)d_in[2];
  const float* bq = (const float*)d_in[3];
  const float* wk = (const float*)d_in[4];
  const float* bk = (const float*)d_in[5];
  const float* wv = (const float*)d_in[6];
  const float* bv = (const float*)d_in[7];
  const float* wo = (const float*)d_in[8];

  float* out = (float*)d_out;                       // [T, 3584]
  float* kv_out = out + (long)T_TOK * NQD;          // [T, 1024] (kv_fused)

  char* ws = (char*)d_ws;
  short* hid_bf  = (short*)(ws);                    // T*3584 bf16
  short* wqkvT   = (short*)(ws + 29360128);         // [4608][3584] bf16
  short* woT     = (short*)(ws + 62390272);         // [3584][3584] bf16
  float* biasc   = (float*)(ws + 88080384);         // 4608 f32
  short* q_bf    = (short*)(ws + 88098816);         // T*3584 bf16
  float* kraw    = (float*)(ws + 117458944);        // T*512 f32
  short* k_bf    = (short*)(ws + 125847552);        // T*512 bf16
  short* vt_g    = (short*)(ws + 130041856);        // [16*128][1024] bf16
  short* attn_bf = (short*)(ws + 134236160);        // T*3584 bf16

  cast_hidden<<<(T_TOK * HIDDEN / 4 + 255) / 256, 256, 0, stream>>>(
      hidden, hid_bf, T_TOK * HIDDEN / 4);
  concat_bias<<<(QKV_N + 255) / 256, 256, 0, stream>>>(bq, bk, bv, biasc);
  transpose_cast64<<<dim3(NQD / 64, HIDDEN / 64), 256, 0, stream>>>(wq, wqkvT, HIDDEN, NQD);
  transpose_cast64<<<dim3(NKVD / 64, HIDDEN / 64), 256, 0, stream>>>(
      wk, wqkvT + (long)NQD * HIDDEN, HIDDEN, NKVD);
  transpose_cast64<<<dim3(NKVD / 64, HIDDEN / 64), 256, 0, stream>>>(
      wv, wqkvT + (long)(NQD + NKVD) * HIDDEN, HIDDEN, NKVD);
  transpose_cast64<<<dim3(HIDDEN / 64, NQD / 64), 256, 0, stream>>>(wo, woT, NQD, HIDDEN);

  gemm_bt128<<<(QKV_N / 128) * (T_TOK / 128), 256, 0, stream>>>(
      hid_bf, wqkvT, T_TOK, QKV_N, HIDDEN, biasc, nullptr, q_bf, kraw, kv_out, 1);

  vtrans64<<<dim3(NKVD / 64, T_TOK / 64), 256, 0, stream>>>(kv_out, vt_g);

  rope_kernel<<<T_TOK, 256, 0, stream>>>(q_bf, positions, kraw, kv_out, k_bf);

  attn_kernel<<<4 * NQ * 16, 256, 0, stream>>>(q_bf, k_bf, vt_g, attn_bf);

  gemm_bt128<<<(HIDDEN / 128) * (T_TOK / 128), 256, 0, stream>>>(
      attn_bf, woT, T_TOK, HIDDEN, HIDDEN, nullptr, out, nullptr, nullptr, nullptr, 0);
}